// Round 3
// baseline (6944.584 us; speedup 1.0000x reference)
//
#include <hip/hip_runtime.h>
#include <math.h>

#define H       256
#define TB      32      // samples per workgroup
#define NT      256     // threads per workgroup (4 waves)
#define NSTEPS  32
#define XS      264     // bf16 elems per activation row: 528B, 16B-aligned

typedef __attribute__((ext_vector_type(8)))  short short8v;   // MFMA A/B frag: 8 bf16
typedef __attribute__((ext_vector_type(16))) float f32x16;    // MFMA C/D frag

__device__ __forceinline__ float fast_tanh(float x) {
    x = fminf(fmaxf(x, -15.0f), 15.0f);
    float e = __expf(2.0f * x);
    return 1.0f - 2.0f / (e + 1.0f);
}

// fp32 -> bf16 bits, round-to-nearest-even
__device__ __forceinline__ unsigned short f2b(float x) {
    unsigned u = __float_as_uint(x);
    u += 0x7FFFu + ((u >> 16) & 1u);
    return (unsigned short)(u >> 16);
}

// ---- pre-pass: fp32 W2,W3 -> bf16 row-major + transposed copies in d_ws ----
__global__ void convert_w(const float* __restrict__ W2, const float* __restrict__ W3,
                          unsigned short* __restrict__ wsb) {
    int t = blockIdx.x * blockDim.x + threadIdx.x;   // 0..65535
    int i = t >> 8, j = t & 255;
    float w2 = W2[t], w3 = W3[t];
    wsb[t]                         = f2b(w2);
    wsb[65536 + t]                 = f2b(w3);
    wsb[131072 + (j << 8) + i]     = f2b(w2);   // W2T[j][i] = W2[i][j]
    wsb[196608 + (j << 8) + i]     = f2b(w3);
}

// one 32x32 output tile: C[n0+row][m] = sum_k Wg[n0+row][k] * X[m][k]
__device__ __forceinline__ f32x16 tile_mfma(const short* __restrict__ Wg, int n0,
                                            int col, int q, const short8v* bvv) {
    f32x16 acc = {};
    const short* ap = Wg + ((n0 + col) << 8) + q * 8;
    #pragma unroll
    for (int kc = 0; kc < 16; ++kc) {
        short8v a = *reinterpret_cast<const short8v*>(ap + kc * 16);
        acc = __builtin_amdgcn_mfma_f32_32x32x16_bf16(a, bvv[kc], acc, 0, 0, 0);
    }
    return acc;
}

#define LOAD_BV(Xsrc)                                                          \
    short8v bvv[16];                                                           \
    _Pragma("unroll")                                                          \
    for (int kc = 0; kc < 16; ++kc)                                            \
        bvv[kc] = *reinterpret_cast<const short8v*>(&Xsrc[col][kc * 16 + q * 8]);

__global__ __launch_bounds__(NT, 4)
void sympnet_mfma(const float* __restrict__ t_eval,
                  const float* __restrict__ state0,
                  const float* __restrict__ W1, const float* __restrict__ b1,
                  const float* __restrict__ b2, const float* __restrict__ b3,
                  const float* __restrict__ W4, const float* __restrict__ scale_p,
                  const short* __restrict__ W2b,  const short* __restrict__ W3b,
                  const short* __restrict__ W2Tb, const short* __restrict__ W3Tb,
                  float* __restrict__ out)
{
    __shared__ unsigned short Xa[TB][XS];   // 16896 B
    __shared__ unsigned short Xb[TB][XS];   // 16896 B
    __shared__ float sS[TB][4];             //   512 B
    __shared__ float gp[4][TB][4];          //  2048 B   -> total 36352 B, 4 blocks/CU

    const int tid  = threadIdx.x;
    const int lane = tid & 63;
    const int wv   = tid >> 6;      // wave 0..3
    const int col  = lane & 31;     // sample index within tile (M of B/C frag)
    const int q    = lane >> 5;

    const float dt    = t_eval[1] - t_eval[0];
    const float scale = scale_p[0];
    const int   b0    = blockIdx.x * TB;

    if (tid < TB) {
        float4 s = reinterpret_cast<const float4*>(state0)[b0 + tid];
        sS[tid][0] = s.x; sS[tid][1] = s.y; sS[tid][2] = s.z; sS[tid][3] = s.w;
        reinterpret_cast<float4*>(out)[(size_t)(b0 + tid) * NSTEPS] = s;
    }
    __syncthreads();

    float d1[32];   // (1 - h1^2), laid out [ti*16 + g*4 + rr] to match B2 epilogue
    float d2[32];   // (1 - h2^2), same layout

    for (int t = 1; t < NSTEPS; ++t) {
        // ========== L1 (VALU): h1 = tanh(s @ W1^T + b1) -> Xa; d1 -> regs
        // thread (wv,col,q) computes h1[col][j] for j = wv*64 + ti*32 + 8g + 4q + rr
        // -- exactly the (sample, j) set it consumes in the B2 epilogue.
        {
            float4 sv = *reinterpret_cast<const float4*>(&sS[col][0]);
            #pragma unroll
            for (int ti = 0; ti < 2; ++ti) {
                #pragma unroll
                for (int g = 0; g < 4; ++g) {
                    const int j = wv * 64 + ti * 32 + 8 * g + 4 * q;
                    float4 bv = *reinterpret_cast<const float4*>(&b1[j]);
                    const float* bp = reinterpret_cast<const float*>(&bv);
                    unsigned short hb[4];
                    #pragma unroll
                    for (int rr = 0; rr < 4; ++rr) {
                        float4 w = reinterpret_cast<const float4*>(W1)[j + rr];
                        float z = bp[rr] + sv.x * w.x + sv.y * w.y
                                         + sv.z * w.z + sv.w * w.w;
                        float h = fast_tanh(z);
                        d1[ti * 16 + g * 4 + rr] = fmaf(-h, h, 1.0f);
                        hb[rr] = f2b(h);
                    }
                    *reinterpret_cast<short4*>(&Xa[col][j]) =
                        make_short4(hb[0], hb[1], hb[2], hb[3]);
                }
            }
        }
        __syncthreads();

        // ========== L2 (MFMA): h2 = tanh(W2 h1 + b2) -> Xb, d2 regs
        {
            LOAD_BV(Xa);
            #pragma unroll
            for (int ti = 0; ti < 2; ++ti) {
                const int n0 = wv * 64 + ti * 32;
                float4 bv4[4];
                #pragma unroll
                for (int g = 0; g < 4; ++g)
                    bv4[g] = *reinterpret_cast<const float4*>(&b2[n0 + 8*g + 4*q]);
                f32x16 acc = tile_mfma(W2b, n0, col, q, bvv);
                #pragma unroll
                for (int g = 0; g < 4; ++g) {
                    const float* bp = reinterpret_cast<const float*>(&bv4[g]);
                    unsigned short hb[4];
                    #pragma unroll
                    for (int rr = 0; rr < 4; ++rr) {
                        float h = fast_tanh(acc[4*g + rr] + bp[rr]);
                        d2[ti*16 + 4*g + rr] = fmaf(-h, h, 1.0f);
                        hb[rr] = f2b(h);
                    }
                    *reinterpret_cast<short4*>(&Xb[col][n0 + 8*g + 4*q]) =
                        make_short4(hb[0], hb[1], hb[2], hb[3]);
                }
            }
        }
        __syncthreads();

        // ========== L3 (MFMA): u3 = W4 ⊙ (1 - tanh^2(W3 h2 + b3)) -> Xa
        {
            LOAD_BV(Xb);
            #pragma unroll
            for (int ti = 0; ti < 2; ++ti) {
                const int n0 = wv * 64 + ti * 32;
                float4 bv4[4], wv4[4];
                #pragma unroll
                for (int g = 0; g < 4; ++g) {
                    bv4[g] = *reinterpret_cast<const float4*>(&b3[n0 + 8*g + 4*q]);
                    wv4[g] = *reinterpret_cast<const float4*>(&W4[n0 + 8*g + 4*q]);
                }
                f32x16 acc = tile_mfma(W3b, n0, col, q, bvv);
                #pragma unroll
                for (int g = 0; g < 4; ++g) {
                    const float* bp = reinterpret_cast<const float*>(&bv4[g]);
                    const float* wp = reinterpret_cast<const float*>(&wv4[g]);
                    unsigned short ub[4];
                    #pragma unroll
                    for (int rr = 0; rr < 4; ++rr) {
                        float h = fast_tanh(acc[4*g + rr] + bp[rr]);
                        ub[rr] = f2b(wp[rr] * fmaf(-h, h, 1.0f));
                    }
                    *reinterpret_cast<short4*>(&Xa[col][n0 + 8*g + 4*q]) =
                        make_short4(ub[0], ub[1], ub[2], ub[3]);
                }
            }
        }
        __syncthreads();

        // ========== B1 (MFMA): u2 = (W3^T u3) ⊙ d2 -> Xb
        {
            LOAD_BV(Xa);
            #pragma unroll
            for (int ti = 0; ti < 2; ++ti) {
                const int n0 = wv * 64 + ti * 32;
                f32x16 acc = tile_mfma(W3Tb, n0, col, q, bvv);
                #pragma unroll
                for (int g = 0; g < 4; ++g) {
                    unsigned short ub[4];
                    #pragma unroll
                    for (int rr = 0; rr < 4; ++rr)
                        ub[rr] = f2b(acc[4*g + rr] * d2[ti*16 + 4*g + rr]);
                    *reinterpret_cast<short4*>(&Xb[col][n0 + 8*g + 4*q]) =
                        make_short4(ub[0], ub[1], ub[2], ub[3]);
                }
            }
        }
        __syncthreads();

        // ===== B2 (MFMA) + B3 fold: u1 = (W2^T u2) ⊙ d1; g[m][c] += u1·W1[n][c]
        {
            float pg0 = 0.f, pg1 = 0.f, pg2 = 0.f, pg3 = 0.f;
            #pragma unroll
            for (int ti = 0; ti < 2; ++ti) {
                const int n0 = wv * 64 + ti * 32;
                f32x16 acc = {};
                const short* ap = W2Tb + ((n0 + col) << 8) + q * 8;
                #pragma unroll
                for (int kc = 0; kc < 16; ++kc) {
                    short8v a = *reinterpret_cast<const short8v*>(ap + kc * 16);
                    short8v b = *reinterpret_cast<const short8v*>(&Xb[col][kc*16 + q*8]);
                    acc = __builtin_amdgcn_mfma_f32_32x32x16_bf16(a, b, acc, 0, 0, 0);
                }
                #pragma unroll
                for (int g = 0; g < 4; ++g) {
                    #pragma unroll
                    for (int rr = 0; rr < 4; ++rr) {
                        float u1 = acc[4*g + rr] * d1[ti*16 + 4*g + rr];
                        float4 w = reinterpret_cast<const float4*>(W1)[n0 + 8*g + 4*q + rr];
                        pg0 = fmaf(u1, w.x, pg0); pg1 = fmaf(u1, w.y, pg1);
                        pg2 = fmaf(u1, w.z, pg2); pg3 = fmaf(u1, w.w, pg3);
                    }
                }
            }
            // combine the two k-halves (q=0,1) within the wave
            pg0 += __shfl_xor(pg0, 32); pg1 += __shfl_xor(pg1, 32);
            pg2 += __shfl_xor(pg2, 32); pg3 += __shfl_xor(pg3, 32);
            if (q == 0)
                *reinterpret_cast<float4*>(&gp[wv][col][0]) =
                    make_float4(pg0, pg1, pg2, pg3);
        }
        __syncthreads();

        // ========== state update (fp32 Verlet + correction)
        if (tid < TB) {
            float g0 = 0.f, g1 = 0.f, g2 = 0.f, g3 = 0.f;
            #pragma unroll
            for (int w = 0; w < 4; ++w) {
                float4 p = *reinterpret_cast<const float4*>(&gp[w][tid][0]);
                g0 += p.x; g1 += p.y; g2 += p.z; g3 += p.w;
            }
            float c0 = g1, c1 = -g0, c2 = g3, c3 = -g2;
            float nrm = sqrtf(c0*c0 + c1*c1 + c2*c2 + c3*c3);
            float ad  = dt * fminf(fmaxf(1.0f - 0.1f * nrm, 0.5f), 1.0f);
            float q1  = sS[tid][0], p1v = sS[tid][1];
            float q2  = sS[tid][2], p2v = sS[tid][3];
            float F1  = -q1 * (1.0f + 2.0f * q2);
            float F2  = -(q2 + q1 * q1 - q2 * q2);
            float p1h = p1v + 0.5f * dt * F1;
            float p2h = p2v + 0.5f * dt * F2;
            float q1n = q1 + dt * p1h;
            float q2n = q2 + dt * p2h;
            float F1n = -q1n * (1.0f + 2.0f * q2n);
            float F2n = -(q2n + q1n * q1n - q2n * q2n);
            float p1n = p1h + 0.5f * dt * F1n;
            float p2n = p2h + 0.5f * dt * F2n;
            float as  = ad * scale;
            float ns0 = q1n + as * c0;
            float ns1 = p1n + as * c1;
            float ns2 = q2n + as * c2;
            float ns3 = p2n + as * c3;
            sS[tid][0] = ns0; sS[tid][1] = ns1; sS[tid][2] = ns2; sS[tid][3] = ns3;
            reinterpret_cast<float4*>(out)[(size_t)(b0 + tid) * NSTEPS + t] =
                make_float4(ns0, ns1, ns2, ns3);
        }
        __syncthreads();
    }
}

extern "C" void kernel_launch(void* const* d_in, const int* in_sizes, int n_in,
                              void* d_out, int out_size, void* d_ws, size_t ws_size,
                              hipStream_t stream) {
    const float* t_eval = (const float*)d_in[0];
    const float* state0 = (const float*)d_in[1];
    const float* W1     = (const float*)d_in[2];
    const float* b1     = (const float*)d_in[3];
    const float* W2     = (const float*)d_in[4];
    const float* b2     = (const float*)d_in[5];
    const float* W3     = (const float*)d_in[6];
    const float* b3     = (const float*)d_in[7];
    const float* W4     = (const float*)d_in[8];
    const float* scale  = (const float*)d_in[10];
    float* out = (float*)d_out;

    unsigned short* wsb = (unsigned short*)d_ws;
    convert_w<<<dim3(256), dim3(256), 0, stream>>>(W2, W3, wsb);

    const short* W2b  = (const short*)(wsb);
    const short* W3b  = (const short*)(wsb + 65536);
    const short* W2Tb = (const short*)(wsb + 131072);
    const short* W3Tb = (const short*)(wsb + 196608);

    const int batch = in_sizes[1] / 4;   // 32768 -> grid 1024 = 4 blocks/CU * 256 CUs
    sympnet_mfma<<<dim3(batch / TB), dim3(NT), 0, stream>>>(
        t_eval, state0, W1, b1, b2, b3, W4, scale,
        W2b, W3b, W2Tb, W3Tb, out);
}